// Round 4
// baseline (546.530 us; speedup 1.0000x reference)
//
#include <hip/hip_runtime.h>
#include <cstddef>

#define T_STEPS 205
#define BATCH   2048
#define NIN     33
#define NRNN    256
#define BB      8           // batch rows per block
#define NTHREADS 512        // 8 waves, 2 per SIMD
#define NTW     2           // n-tiles (16 cols) per wave

// K layout: k = 0..255 -> h[k] (W row 33+k), k = 256..287 -> x[0..31]
// (W rows 0..31), rank-1: x[32] (W row 32) via VALU in the epilogue.
// t-loop has ZERO global loads (R3 confirmed: in-loop vmcnt retirement was
// serializing each step on the previous step's HBM stores).
//
// R4: LDS-pressure cuts.
//  - am = nlo&7 broadcast: C rows 8..15 are never consumed, so lanes 8..15
//    read the SAME A/x addresses as lanes 0..7 -> LDS broadcast halves bank
//    work on every b128 frag read (8-way -> 4-way, the floor for this shape).
//    A buffer shrinks to 8 real rows, no zero padding needed at all.
//  - x[32] stored as f32 in a tiny side array: ONE ds_read_b128 (2 unique
//    addrs/wave) replaces 4 ds_read_u16.
//  - next-t x fragments prefetched BEFORE the barrier (x region is loop-
//    invariant, no hazard) -> post-barrier critical path is A-reads only.

#define A_STRIDE  264       // fp16; 528B row stride -> 4-mod-32 dword classes
#define X_BSTRIDE 32        // fp16 x row: exactly x[0..31]
#define X_TSTRIDE (BB * X_BSTRIDE)   // 256 fp16 per t
#define WS_STRIDE 40        // fp16 elems per W-stage row

typedef _Float16 half8 __attribute__((ext_vector_type(8)));
typedef float    f32x4 __attribute__((ext_vector_type(4)));
typedef unsigned int uintx2 __attribute__((ext_vector_type(2)));

// Barrier that waits ONLY on LDS ops (lgkmcnt), never vmcnt.
__device__ __forceinline__ void lds_barrier() {
    asm volatile("s_waitcnt lgkmcnt(0)\n\ts_barrier" ::: "memory");
}

// result = {a.lanes[0..31], b.lanes[0..31]}
__device__ __forceinline__ float permlane_merge(float a, float b) {
    uintx2 r = __builtin_amdgcn_permlane32_swap(
        __builtin_bit_cast(unsigned int, a),
        __builtin_bit_cast(unsigned int, b), false, false);
    return __builtin_bit_cast(float, r[0]);
}

__device__ __forceinline__ int grow(int kk) {   // gemm-k -> W row
    return (kk < NRNN) ? (33 + kk) : (kk - NRNN);
}

__global__ __launch_bounds__(NTHREADS, 1)
void leaky_rnn_kernel(const float* __restrict__ x,
                      const float* __restrict__ W,
                      const float* __restrict__ bias,
                      const float* __restrict__ h0,
                      float* __restrict__ out)
{
    // A: h only, 8 rows, double-buffered (8.4 KB).
    // X: full x slice fp16 [t][b][32] (105 KB; W-staging aliases its head).
    // X32: x[32] per (t,b) as f32 (6.6 KB).  Total ~120 KB < 160 KB.
    __shared__ __align__(16) _Float16 A_lds[2][8 * A_STRIDE];
    __shared__ __align__(16) _Float16 X_lds[T_STEPS * X_TSTRIDE];
    __shared__ __align__(16) float    X32[T_STEPS * BB];

    const int tid  = threadIdx.x;
    const int lane = tid & 63;
    const int wave = tid >> 6;      // 0..7
    const int q    = lane >> 4;     // quad 0..3
    const int nlo  = lane & 15;
    const int qe   = q & 1;         // post-merge row group: rows qe*4 + r
    const int hi   = lane >> 5;     // 0: even n-tile of pair, 1: odd
    const int b0   = blockIdx.x * BB;

    // ---- one-time: stage W (permuted rows, fp32->fp16), pull B-frags ----
    _Float16* Wst = &X_lds[0];      // dead after init; x preload reuses it
    half8 wfrag[NTW][9];
    {
        const int c   = tid & 255;  // W column this thread packs
        const int oct = tid >> 8;   // 0..1
        #pragma unroll
        for (int kt = 0; kt < 9; ++kt) {
            __syncthreads();
            #pragma unroll
            for (int o2 = 0; o2 < 2; ++o2) {
                int o = oct + 2 * o2;       // k-octet 0..3 within 32-chunk
                half8 pack;
                #pragma unroll
                for (int i = 0; i < 8; ++i)
                    pack[i] = (_Float16)W[grow(kt * 32 + o * 8 + i) * NRNN + c];
                *(half8*)&Wst[c * WS_STRIDE + o * 8] = pack;
            }
            __syncthreads();
            #pragma unroll
            for (int nt = 0; nt < NTW; ++nt) {
                int n = wave * 32 + nt * 16 + nlo;
                wfrag[nt][kt] = *(const half8*)&Wst[n * WS_STRIDE + q * 8];
            }
        }
        __syncthreads();   // all frag reads done before x preload clobbers Wst
    }

    // per-lane epilogue constants (post-merge layout)
    const int   ecol = wave * 32 + hi * 16 + nlo;   // 0..255
    const float bve  = bias[ecol];
    const float w32e = W[32 * NRNN + ecol];         // rank-1 row (x[32])

    // ---- preload ALL x for this block: fp32 global -> LDS ----
    for (int e = tid; e < T_STEPS * (BB * NIN); e += NTHREADS) {
        int t  = e / (BB * NIN);
        int i  = e - t * (BB * NIN);
        int b  = i / NIN;
        int xi = i - b * NIN;
        float v = x[(size_t)t * (BATCH * NIN) + (size_t)b0 * NIN + i];
        if (xi < 32) X_lds[t * X_TSTRIDE + b * X_BSTRIDE + xi] = (_Float16)v;
        else         X32[t * BB + b] = v;
    }

    // ---- h0 -> A buf0 + registers ----
    float hreg[4];
    #pragma unroll
    for (int r = 0; r < 4; ++r) {
        int b = qe * 4 + r;
        float h = h0[(b0 + b) * NRNN + ecol];
        hreg[r] = h;
        A_lds[0][b * A_STRIDE + ecol] = (_Float16)h;
    }
    __syncthreads();   // end of init

    const int am = nlo & 7;   // broadcast: lanes 8..15 mirror 0..7
    half8 xf   = *(const half8*)&X_lds[am * X_BSTRIDE + q * 8];
    f32x4 x32v = *(const f32x4*)&X32[qe * 4];

    int p = 0;
    for (int t = 0; t < T_STEPS; ++t) {
        const _Float16* __restrict__ Ar = A_lds[p];
        _Float16* __restrict__ Aw = A_lds[p ^ 1];

        // split-K accumulators: 4 independent MFMA chains per wave
        f32x4 acc[NTW][2];
        #pragma unroll
        for (int nt = 0; nt < NTW; ++nt)
            #pragma unroll
            for (int s = 0; s < 2; ++s) acc[nt][s] = (f32x4){0.f, 0.f, 0.f, 0.f};

        #pragma unroll
        for (int kt = 0; kt < 8; ++kt) {
            half8 af = *(const half8*)&Ar[am * A_STRIDE + kt * 32 + q * 8];
            acc[0][kt & 1] = __builtin_amdgcn_mfma_f32_16x16x32_f16(af, wfrag[0][kt], acc[0][kt & 1], 0, 0, 0);
            acc[1][kt & 1] = __builtin_amdgcn_mfma_f32_16x16x32_f16(af, wfrag[1][kt], acc[1][kt & 1], 0, 0, 0);
        }
        acc[0][0] = __builtin_amdgcn_mfma_f32_16x16x32_f16(xf, wfrag[0][8], acc[0][0], 0, 0, 0);
        acc[1][0] = __builtin_amdgcn_mfma_f32_16x16x32_f16(xf, wfrag[1][8], acc[1][0], 0, 0, 0);

        f32x4 s0 = acc[0][0] + acc[0][1];
        f32x4 s1 = acc[1][0] + acc[1][1];

        // merge n-tile pair across lane halves; epilogue on ALL 64 lanes.
        float hn_[4];
        #pragma unroll
        for (int r = 0; r < 4; ++r) {
            float m   = permlane_merge(s0[r], s1[r]);
            float pre = m + bve + x32v[r] * w32e;
            float hn  = 0.8f * hreg[r] + 0.2f * fmaxf(pre, 0.f);
            hreg[r] = hn;
            hn_[r]  = hn;
            Aw[(qe * 4 + r) * A_STRIDE + ecol] = (_Float16)hn;   // LDS first
        }

        // prefetch next-t x fragments (loop-invariant region, no hazard):
        // overlaps with the h ds_write drain, off the post-barrier path.
        const int tn = (t + 1 < T_STEPS) ? (t + 1) : t;
        half8 xf_n   = *(const half8*)&X_lds[tn * X_TSTRIDE + am * X_BSTRIDE + q * 8];
        f32x4 x32v_n = *(const f32x4*)&X32[tn * BB + qe * 4];

        float* op = out + ((size_t)t * BATCH + b0 + qe * 4) * NRNN + ecol;
        #pragma unroll
        for (int r = 0; r < 4; ++r)                               // then HBM
            __builtin_nontemporal_store(hn_[r], op + (size_t)r * NRNN);

        lds_barrier();   // lgkmcnt only; stores are never waited on
        xf = xf_n; x32v = x32v_n;
        p ^= 1;
    }
}

extern "C" void kernel_launch(void* const* d_in, const int* in_sizes, int n_in,
                              void* d_out, int out_size, void* d_ws, size_t ws_size,
                              hipStream_t stream) {
    const float* x    = (const float*)d_in[0];
    const float* W    = (const float*)d_in[1];   // (289, 256) row-major
    const float* bias = (const float*)d_in[2];
    const float* h0   = (const float*)d_in[3];
    float* out = (float*)d_out;

    dim3 grid(BATCH / BB);      // 256 blocks -> 1 per CU
    dim3 block(NTHREADS);       // 8 waves
    leaky_rnn_kernel<<<grid, block, 0, stream>>>(x, W, bias, h0, out);
}